// Round 7
// baseline (84.576 us; speedup 1.0000x reference)
//
#include <hip/hip_runtime.h>
#include <hip/hip_bf16.h>

#define NN 16384
#define DD 64
#define UTOT 32896             // sum_{s=0}^{255} (256 - s): 64x64 triangular units
#define NBLK 1024
#define NWAVES 4096            // NBLK * 4
#define NPOSB (NN/4)
#define SCREEN_T 0.49f         // hinge>0 needs gram > ~0.5-3e-5; bf16 err ~4e-3

constexpr float F_EPS_PD   = 1e-6f;
constexpr float F_EPS_NORM = 1e-6f;

using bf16x8 = __attribute__((ext_vector_type(8))) short;
using f32x4  = __attribute__((ext_vector_type(4))) float;

__device__ __forceinline__ float wave_sum_f(float v) {
    #pragma unroll
    for (int o = 32; o >= 1; o >>= 1) v += __shfl_xor(v, o);
    return v;
}

// units for strip s: cols c in [s, 256) -> offset(s) = 256s - s(s-1)/2
__device__ __forceinline__ int strip_off(int s) { return 256 * s - (s * (s - 1)) / 2; }

// ---------------------------------------------------------------------------
// Kernel 1: per-row normalize + bf16 copy + packed {u,lab} / {vc,lab} + exact
// fp32 positive-pair loss.
//   u[i]  = sq_i + 2*eps*s_i ;  vc[j] = sq_j - 2*eps*s_j + D*eps^2
//   d2(i,j) = u_i + vc_j - 2*gram(i,j)
// ---------------------------------------------------------------------------
__global__ __launch_bounds__(256) void norm_kernel(
    const float* __restrict__ emb, const int* __restrict__ pidx,
    const int* __restrict__ lab, float2* __restrict__ up,
    float2* __restrict__ vcp, __hip_bfloat16* __restrict__ ebf,
    float* __restrict__ posP) {
    int w    = threadIdx.x >> 6;
    int row  = blockIdx.x * 4 + w;
    int lane = threadIdx.x & 63;
    int j    = pidx[row];
    float x  = emb[(size_t)row * DD + lane];
    float xj = emb[(size_t)j   * DD + lane];

    float n2  = wave_sum_f(x * x);
    float sx  = wave_sum_f(x);
    float n2j = wave_sum_f(xj * xj);
    float sxj = wave_sum_f(xj);
    float dot = wave_sum_f(x * xj);

    float m  = fmaxf(sqrtf(n2),  F_EPS_NORM);
    float mj = fmaxf(sqrtf(n2j), F_EPS_NORM);
    ebf[(size_t)row * DD + lane] = __float2bfloat16(x / m);

    __shared__ float spos[4];
    if (lane == 0) {
        float sq  = n2 / (m * m);
        float sqj = n2j / (mj * mj);
        float s   = sx / m;
        float sj  = sxj / mj;
        float g   = dot / (m * mj);
        float lf  = (float)lab[row];
        up[row]  = make_float2(sq + 2.0f * F_EPS_PD * s, lf);
        vcp[row] = make_float2(
            sq - 2.0f * F_EPS_PD * s + (float)DD * F_EPS_PD * F_EPS_PD, lf);
        float d2p = sq + sqj - 2.0f * g + 2.0f * F_EPS_PD * (s - sj)
                  + (float)DD * F_EPS_PD * F_EPS_PD;
        spos[w] = fmaxf(d2p, 0.0f);
    }
    __syncthreads();
    if (threadIdx.x == 0)
        posP[blockIdx.x] = spos[0] + spos[1] + spos[2] + spos[3];
}

// ---------------------------------------------------------------------------
// Kernel 2: wave-autonomous. Unit = (64-row strip s, 64-col half c), c>=s.
// Each wave owns a contiguous range of the 32896 units (strip-major), keeps
// A-frags (8 VGPR-pairs) across a strip run, double-buffers B-frags in
// registers (bA/bB, static indexing), no LDS, no barriers in the hot loop.
// Weight: c==s diag 1 (both orders in-block; i==j drops via equal labels),
// c>s upper 2 (antisym eps term ~0.1 total vs ~655 budget).
// Screen: hinge needs gram > ~0.5; rare (~2-5%) path gathers {u,lab},{vc,lab}.
// ---------------------------------------------------------------------------
#define LOADB(BUF, cc_)                                                        \
    do {                                                                       \
        const short* bb_ = ebf + (size_t)((cc_) * 64 + lrow) * DD + lkh * 8;   \
        BUF[0][0] = *(const bf16x8*)(bb_);                                     \
        BUF[0][1] = *(const bf16x8*)(bb_ + 32);                                \
        BUF[1][0] = *(const bf16x8*)(bb_ + 16 * DD);                           \
        BUF[1][1] = *(const bf16x8*)(bb_ + 16 * DD + 32);                      \
        BUF[2][0] = *(const bf16x8*)(bb_ + 32 * DD);                           \
        BUF[2][1] = *(const bf16x8*)(bb_ + 32 * DD + 32);                      \
        BUF[3][0] = *(const bf16x8*)(bb_ + 48 * DD);                           \
        BUF[3][1] = *(const bf16x8*)(bb_ + 48 * DD + 32);                      \
    } while (0)

#define COMPUTE(BUF, cc_)                                                      \
    do {                                                                       \
        int jb_ = (cc_) * 64;                                                  \
        float wgt_ = ((cc_) == s) ? 1.0f : 2.0f;                               \
        float hp_ = 0.0f;                                                      \
        _Pragma("unroll")                                                      \
        for (int t_ = 0; t_ < 4; ++t_) {                                       \
            f32x4 cc4[4];                                                      \
            _Pragma("unroll")                                                  \
            for (int k_ = 0; k_ < 4; ++k_) {                                   \
                f32x4 z_ = {0.f, 0.f, 0.f, 0.f};                               \
                z_ = __builtin_amdgcn_mfma_f32_16x16x32_bf16(a[k_][0], BUF[t_][0], z_, 0, 0, 0); \
                z_ = __builtin_amdgcn_mfma_f32_16x16x32_bf16(a[k_][1], BUF[t_][1], z_, 0, 0, 0); \
                cc4[k_] = z_;                                                  \
            }                                                                  \
            float mx_ = fmaxf(fmaxf(cc4[0][0], cc4[0][1]), fmaxf(cc4[0][2], cc4[0][3])); \
            mx_ = fmaxf(mx_, fmaxf(fmaxf(cc4[1][0], cc4[1][1]), fmaxf(cc4[1][2], cc4[1][3]))); \
            mx_ = fmaxf(mx_, fmaxf(fmaxf(cc4[2][0], cc4[2][1]), fmaxf(cc4[2][2], cc4[2][3]))); \
            mx_ = fmaxf(mx_, fmaxf(fmaxf(cc4[3][0], cc4[3][1]), fmaxf(cc4[3][2], cc4[3][3]))); \
            if (__any(mx_ > SCREEN_T)) {                                       \
                float2 vl_ = vcp[jb_ + t_ * 16 + lrow];                        \
                _Pragma("unroll")                                              \
                for (int k_ = 0; k_ < 4; ++k_) {                               \
                    _Pragma("unroll")                                          \
                    for (int r_ = 0; r_ < 4; ++r_) {                           \
                        float2 ul_ = up[rowbase + 16 * k_ + lkh * 4 + r_];     \
                        float d2_ = fmaf(-2.0f, cc4[k_][r_], ul_.x + vl_.x);   \
                        float d_  = sqrtf(fmaxf(d2_, 1e-12f));                 \
                        float h_  = fmaxf(1.0f - d_, 0.0f);                    \
                        if (ul_.y != vl_.y) hp_ = fmaf(h_, h_, hp_);           \
                    }                                                          \
                }                                                              \
            }                                                                  \
        }                                                                      \
        hacc = fmaf(wgt_, hp_, hacc);                                          \
    } while (0)

__global__ __launch_bounds__(256, 4) void pair_kernel(
    const short* __restrict__ ebf, const float2* __restrict__ up,
    const float2* __restrict__ vcp, float* __restrict__ negP) {
    int tid  = threadIdx.x;
    int w    = tid >> 6;
    int lane = tid & 63;
    int lrow = lane & 15, lkh = lane >> 4;
    int gw   = blockIdx.x * 4 + w;

    int us = (int)(((long long)gw * UTOT) / NWAVES);
    int ue = (int)(((long long)(gw + 1) * UTOT) / NWAVES);

    // decode us -> strip s
    int s = (int)(256.5f - sqrtf(256.5f * 256.5f - 2.0f * (float)us));
    s = s < 0 ? 0 : (s > 255 ? 255 : s);
    while (strip_off(s) > us) --s;
    while (s < 255 && strip_off(s + 1) <= us) ++s;

    float hacc = 0.0f;
    int u0 = us;
    while (u0 < ue) {
        int send = strip_off(s + 1);
        int n    = (ue < send ? ue : send) - u0;
        int c0   = s + (u0 - strip_off(s));
        int rowbase = s * 64;

        bf16x8 a[4][2];
        #pragma unroll
        for (int k = 0; k < 4; ++k) {
            const short* ab = ebf + (size_t)(rowbase + 16 * k + lrow) * DD + lkh * 8;
            a[k][0] = *(const bf16x8*)(ab);
            a[k][1] = *(const bf16x8*)(ab + 32);
        }

        bf16x8 bA[4][2], bB[4][2];
        LOADB(bA, c0);
        for (int k = 0; k < n; k += 2) {
            bool h1 = (k + 1 < n);
            if (h1) LOADB(bB, c0 + k + 1);
            COMPUTE(bA, c0 + k);
            if (h1) {
                if (k + 2 < n) LOADB(bA, c0 + k + 2);
                COMPUTE(bB, c0 + k + 1);
            }
        }
        u0 += n;
        ++s;
    }

    hacc = wave_sum_f(hacc);
    __shared__ float sred[4];
    if (lane == 0) sred[w] = hacc;
    __syncthreads();
    if (tid == 0)
        negP[blockIdx.x] = sred[0] + sred[1] + sred[2] + sred[3];
}

// ---------------------------------------------------------------------------
// Kernel 3: final reduction + 4-replica label histogram -> analytic negative
// count: n_neg = N^2 - sum_c n_c^2 ; n_comparisons = N + n_neg
// ---------------------------------------------------------------------------
__global__ __launch_bounds__(256) void reduce_kernel(
    const float* __restrict__ posP, const float* __restrict__ negP,
    const int* __restrict__ lab, float* __restrict__ out) {
    __shared__ unsigned int hist[4][1024];
    int t = threadIdx.x;
    int w = t >> 6, lane = t & 63;
    for (int i = t; i < 4096; i += 256) hist[i >> 10][i & 1023] = 0u;
    __syncthreads();
    const int4* lab4 = (const int4*)lab;
    for (int i = t; i < NN / 4; i += 256) {
        int4 v = lab4[i];
        atomicAdd(&hist[w][v.x & 1023], 1u);
        atomicAdd(&hist[w][v.y & 1023], 1u);
        atomicAdd(&hist[w][v.z & 1023], 1u);
        atomicAdd(&hist[w][v.w & 1023], 1u);
    }
    __syncthreads();

    float ps = 0.f, ns = 0.f;
    unsigned long long sqc = 0u;
    const float4* posP4 = (const float4*)posP;
    for (int i = t; i < NPOSB / 4; i += 256) {
        float4 v = posP4[i];
        ps += (v.x + v.y) + (v.z + v.w);
    }
    for (int i = t; i < NBLK; i += 256) ns += negP[i];
    for (int i = t; i < 1024; i += 256) {
        unsigned long long h = (unsigned long long)hist[0][i] + hist[1][i]
                             + hist[2][i] + hist[3][i];
        sqc += h * h;
    }

    ps = wave_sum_f(ps);
    ns = wave_sum_f(ns);
    #pragma unroll
    for (int o = 32; o >= 1; o >>= 1) sqc += __shfl_xor(sqc, o);

    __shared__ float sp[4], sn[4];
    __shared__ unsigned long long sc[4];
    if (lane == 0) { sp[w] = ps; sn[w] = ns; sc[w] = sqc; }
    __syncthreads();
    if (t == 0) {
        float pos = sp[0] + sp[1] + sp[2] + sp[3];
        float neg = sn[0] + sn[1] + sn[2] + sn[3];
        unsigned long long s2 = sc[0] + sc[1] + sc[2] + sc[3];
        unsigned long long nneg = (unsigned long long)NN * NN - s2;
        float ncomp = (float)((unsigned long long)NN + nneg);
        out[0] = (pos + neg) / ncomp;
    }
}

// ---------------------------------------------------------------------------
// ws layout (bytes):
//   up   @ 0        : 131072  (float2[16384]: {u, label})
//   vcp  @ 131072   : 131072  (float2[16384]: {vc, label})
//   ebf  @ 262144   : 2097152
//   posP @ 2359296  : 16384   (NPOSB floats)
//   negP @ 2375680  : 4096    (NBLK floats)
//   total 2379776
// ---------------------------------------------------------------------------
extern "C" void kernel_launch(void* const* d_in, const int* in_sizes, int n_in,
                              void* d_out, int out_size, void* d_ws, size_t ws_size,
                              hipStream_t stream) {
    const float* emb = (const float*)d_in[0];
    const int* lab   = (const int*)d_in[1];
    const int* pidx  = (const int*)d_in[2];
    float* out = (float*)d_out;
    char* ws = (char*)d_ws;
    float2*         up   = (float2*)(ws);
    float2*         vcp  = (float2*)(ws + 131072);
    __hip_bfloat16* ebf  = (__hip_bfloat16*)(ws + 262144);
    float*          posP = (float*)(ws + 2359296);
    float*          negP = (float*)(ws + 2375680);

    norm_kernel<<<NPOSB, 256, 0, stream>>>(emb, pidx, lab, up, vcp, ebf, posP);
    pair_kernel<<<NBLK, 256, 0, stream>>>((const short*)ebf, up, vcp, negP);
    reduce_kernel<<<1, 256, 0, stream>>>(posP, negP, lab, out);
}

// Round 8
// 53.852 us; speedup vs baseline: 1.5705x; 1.5705x over previous
//
#include <hip/hip_runtime.h>
#include <hip/hip_bf16.h>

#define NN 16384
#define DD 64
#define NBI 32                 // 512-row bands
#define NUNITS 2112            // sum_I (128 - 4I), I=0..31
#define NBLK 512               // 2 blocks/CU
#define NPOSB (NN/4)
#define SCREEN_T 0.49f         // hinge>0 needs gram > ~0.5-3e-5; margin 1e-2

constexpr float F_EPS_PD   = 1e-6f;
constexpr float F_EPS_NORM = 1e-6f;

using bf16x8 = __attribute__((ext_vector_type(8))) short;
using f32x4  = __attribute__((ext_vector_type(4))) float;
typedef __attribute__((address_space(1))) const unsigned int gu32_t;
typedef __attribute__((address_space(3))) unsigned int       lu32_t;

__device__ __forceinline__ float wave_sum_f(float v) {
    #pragma unroll
    for (int o = 32; o >= 1; o >>= 1) v += __shfl_xor(v, o);
    return v;
}

// unit offset of band I (units are (band, col-tile) with tj in [4I,128))
__device__ __forceinline__ int band_off(int I) { return 2 * I * (65 - I); }

// ---------------------------------------------------------------------------
// Kernel 1: per-row normalize + bf16 copy + packed {u,lab}/{vc,lab} + exact
// fp32 positive-pair loss.   d2(i,j) = u_i + vc_j - 2*gram(i,j)
// ---------------------------------------------------------------------------
__global__ __launch_bounds__(256) void norm_kernel(
    const float* __restrict__ emb, const int* __restrict__ pidx,
    const int* __restrict__ lab, float2* __restrict__ up,
    float2* __restrict__ vcp, __hip_bfloat16* __restrict__ ebf,
    float* __restrict__ posP) {
    int w    = threadIdx.x >> 6;
    int row  = blockIdx.x * 4 + w;
    int lane = threadIdx.x & 63;
    int j    = pidx[row];
    float x  = emb[(size_t)row * DD + lane];
    float xj = emb[(size_t)j   * DD + lane];

    float n2  = wave_sum_f(x * x);
    float sx  = wave_sum_f(x);
    float n2j = wave_sum_f(xj * xj);
    float sxj = wave_sum_f(xj);
    float dot = wave_sum_f(x * xj);

    float m  = fmaxf(sqrtf(n2),  F_EPS_NORM);
    float mj = fmaxf(sqrtf(n2j), F_EPS_NORM);
    ebf[(size_t)row * DD + lane] = __float2bfloat16(x / m);

    __shared__ float spos[4];
    if (lane == 0) {
        float sq  = n2 / (m * m);
        float sqj = n2j / (mj * mj);
        float s   = sx / m;
        float sj  = sxj / mj;
        float g   = dot / (m * mj);
        float lf  = (float)lab[row];
        up[row]  = make_float2(sq + 2.0f * F_EPS_PD * s, lf);
        vcp[row] = make_float2(
            sq - 2.0f * F_EPS_PD * s + (float)DD * F_EPS_PD * F_EPS_PD, lf);
        float d2p = sq + sqj - 2.0f * g + 2.0f * F_EPS_PD * (s - sj)
                  + (float)DD * F_EPS_PD * F_EPS_PD;
        spos[w] = fmaxf(d2p, 0.0f);
    }
    __syncthreads();
    if (threadIdx.x == 0)
        posP[blockIdx.x] = spos[0] + spos[1] + spos[2] + spos[3];
}

// ---------------------------------------------------------------------------
// Stage one (B tile 16 KB + vcp slice 1 KB) into a ring slot. 3 ops per wave
// (uniform across waves -> exact vmcnt counts). B source XOR-preswizzled:
// LDS row r, 16B slot c holds global chunk c^(r&7) (both-sides rule; the
// matching read XOR is applied in compute). vcp slice staged redundantly by
// all 8 waves (identical data - benign).
// ---------------------------------------------------------------------------
__device__ __forceinline__ void stage_tile(const short* ebf, const float2* vcp,
                                           int tile, short* slotB, float2* slotV,
                                           int w, int lane) {
    const short* tbase = ebf + (size_t)tile * (128 * DD);
    int rlo = lane >> 3;
    int g   = (lane & 7) ^ rlo;
    #pragma unroll
    for (int q = 0; q < 2; ++q) {
        int m = w * 2 + q;
        __builtin_amdgcn_global_load_lds(
            (gu32_t*)(const void*)(tbase + (size_t)(8 * m + rlo) * DD + g * 8),
            (lu32_t*)(void*)(slotB + m * 512), 16, 0, 0);
    }
    __builtin_amdgcn_global_load_lds(
        (gu32_t*)(const void*)(vcp + (size_t)tile * 128 + lane * 2),
        (lu32_t*)(void*)slotV, 16, 0, 0);
}

// ---------------------------------------------------------------------------
// Kernel 2: 8-wave blocks over (512-row band I, 128-col tile tj), tj>=4I.
// Wave w owns 64 rows (4 strips). Counted-vmcnt ring (3 slots, 2-deep):
//   steady iter: s_waitcnt vmcnt(3) ; s_barrier ; stage(k+2) ; compute(k)
// ZERO vmem in compute: rare-path vc/label from ringV (LDS), u/label from
// uband (LDS, staged per segment) -> vmcnt counts stay exact.
// Per-wave weight vs own col-tile rt=4I+(w>>1): diag 1 / upper 2 / lower 0
// (even/odd wave pair compensates within-diag transposes; verified R5/R6).
// Screen: hinge needs gram > ~0.5; rare (~2-5%) path does exact d2/hinge.
// ---------------------------------------------------------------------------
__global__ __launch_bounds__(512, 4) void pair_kernel(
    const short* __restrict__ ebf, const float2* __restrict__ up,
    const float2* __restrict__ vcp, float* __restrict__ negP) {
    __shared__ short  ringB[3][8192];   // 3 x 16 KB B tiles (swizzled)
    __shared__ float2 ringV[3][128];    // 3 x 1 KB {vc,lab} slices
    __shared__ float2 uband[512];       // band {u,lab}, staged per segment
    __shared__ float  sred[8];
    int tid  = threadIdx.x;
    int w    = tid >> 6;
    int lane = tid & 63;
    int lrow = lane & 15, lkh = lane >> 4;
    int c0s  = ((lkh)     ^ (lrow & 7)) * 8;   // swizzled K[0:32) chunk
    int c1s  = ((lkh + 4) ^ (lrow & 7)) * 8;   // swizzled K[32:64) chunk

    int ks = (int)(((long long)blockIdx.x * NUNITS) / NBLK);
    int ke = (int)(((long long)(blockIdx.x + 1) * NUNITS) / NBLK);

    // decode ks -> band I
    int I = (int)((65.0f - sqrtf(4225.0f - 2.0f * (float)ks)) * 0.5f);
    I = I < 0 ? 0 : (I > NBI - 1 ? NBI - 1 : I);
    while (band_off(I) > ks) --I;
    while (I < NBI - 1 && band_off(I + 1) <= ks) ++I;

    float hacc = 0.0f;
    int u0 = ks;
    while (u0 < ke) {
        int bend = band_off(I + 1);
        int n    = (ke < bend ? ke : bend) - u0;
        int tj0  = 4 * I + (u0 - band_off(I));
        int rowbase = I * 512 + w * 64;
        int rt      = 4 * I + (w >> 1);

        // --- segment prologue: A frags, u-band stage, prime 2 tiles ---
        bf16x8 a[4][2];
        #pragma unroll
        for (int s = 0; s < 4; ++s) {
            const short* ab = ebf + (size_t)(rowbase + 16 * s + lrow) * DD + lkh * 8;
            a[s][0] = *(const bf16x8*)(ab);
            a[s][1] = *(const bf16x8*)(ab + 32);
        }
        if (w < 4)
            __builtin_amdgcn_global_load_lds(
                (gu32_t*)(const void*)(up + (size_t)I * 512 + w * 128 + lane * 2),
                (lu32_t*)(void*)(uband + w * 128), 16, 0, 0);
        stage_tile(ebf, vcp, tj0, &ringB[0][0], &ringV[0][0], w, lane);
        if (n > 1)
            stage_tile(ebf, vcp, tj0 + 1, &ringB[1][0], &ringV[1][0], w, lane);

        int sl = 0;                        // ring slot of tile k
        for (int k = 0; k < n; ++k) {
            // steady: own 3 stage-ops of tile k drained, 2 tiles (6 ops) in flight
            if (k + 1 < n) asm volatile("s_waitcnt vmcnt(3)" ::: "memory");
            else           asm volatile("s_waitcnt vmcnt(0)" ::: "memory");
            __builtin_amdgcn_s_barrier();
            __builtin_amdgcn_sched_barrier(0);
            int sl2 = (sl >= 1) ? sl - 1 : 2;     // slot of tile k+2
            if (k + 2 < n)
                stage_tile(ebf, vcp, tj0 + k + 2, &ringB[sl2][0], &ringV[sl2][0],
                           w, lane);

            int tj = tj0 + k;
            float wgt = (tj == rt) ? 1.0f : ((tj > rt) ? 2.0f : 0.0f);
            if (wgt != 0.0f) {
                const short*  lb = &ringB[sl][0];
                const float2* lv = &ringV[sl][0];
                float hp = 0.0f;
                #pragma unroll
                for (int t = 0; t < 8; ++t) {
                    const short* rowp = lb + (t * 16 + lrow) * 64;
                    bf16x8 b0 = *(const bf16x8*)(rowp + c0s);
                    bf16x8 b1 = *(const bf16x8*)(rowp + c1s);
                    f32x4 c4[4];
                    #pragma unroll
                    for (int s = 0; s < 4; ++s) {
                        f32x4 z = {0.f, 0.f, 0.f, 0.f};
                        z = __builtin_amdgcn_mfma_f32_16x16x32_bf16(a[s][0], b0, z, 0, 0, 0);
                        z = __builtin_amdgcn_mfma_f32_16x16x32_bf16(a[s][1], b1, z, 0, 0, 0);
                        c4[s] = z;
                    }
                    float mx = fmaxf(fmaxf(c4[0][0], c4[0][1]), fmaxf(c4[0][2], c4[0][3]));
                    mx = fmaxf(mx, fmaxf(fmaxf(c4[1][0], c4[1][1]), fmaxf(c4[1][2], c4[1][3])));
                    mx = fmaxf(mx, fmaxf(fmaxf(c4[2][0], c4[2][1]), fmaxf(c4[2][2], c4[2][3])));
                    mx = fmaxf(mx, fmaxf(fmaxf(c4[3][0], c4[3][1]), fmaxf(c4[3][2], c4[3][3])));
                    if (__any(mx > SCREEN_T)) {            // rare; LDS-only path
                        float2 vl = lv[t * 16 + lrow];
                        #pragma unroll
                        for (int s = 0; s < 4; ++s) {
                            #pragma unroll
                            for (int r = 0; r < 4; ++r) {
                                float2 ul = uband[w * 64 + 16 * s + lkh * 4 + r];
                                float d2 = fmaf(-2.0f, c4[s][r], ul.x + vl.x);
                                float d  = sqrtf(fmaxf(d2, 1e-12f));
                                float h  = fmaxf(1.0f - d, 0.0f);
                                if (ul.y != vl.y) hp = fmaf(h, h, hp);
                            }
                        }
                    }
                }
                hacc = fmaf(wgt, hp, hacc);
            }
            sl = (sl + 1 == 3) ? 0 : sl + 1;
        }
        __builtin_amdgcn_s_barrier();      // protect ring/uband reuse
        __builtin_amdgcn_sched_barrier(0);
        u0 += n;
        ++I;
    }

    hacc = wave_sum_f(hacc);
    if (lane == 0) sred[w] = hacc;
    __syncthreads();
    if (tid == 0) {
        float tn = 0.f;
        #pragma unroll
        for (int i = 0; i < 8; ++i) tn += sred[i];
        negP[blockIdx.x] = tn;
    }
}

// ---------------------------------------------------------------------------
// Kernel 3: final reduction + 4-replica label histogram -> analytic negative
// count: n_neg = N^2 - sum_c n_c^2 ; n_comparisons = N + n_neg
// ---------------------------------------------------------------------------
__global__ __launch_bounds__(1024) void reduce_kernel(
    const float* __restrict__ posP, const float* __restrict__ negP,
    const int* __restrict__ lab, float* __restrict__ out) {
    __shared__ unsigned int hist[4][1024];
    int t = threadIdx.x;
    int w = t >> 6, lane = t & 63;
    for (int i = t; i < 4096; i += 1024) hist[i >> 10][i & 1023] = 0u;
    __syncthreads();
    const int4* lab4 = (const int4*)lab;
    for (int i = t; i < NN / 4; i += 1024) {
        int4 v = lab4[i];
        atomicAdd(&hist[w & 3][v.x & 1023], 1u);
        atomicAdd(&hist[w & 3][v.y & 1023], 1u);
        atomicAdd(&hist[w & 3][v.z & 1023], 1u);
        atomicAdd(&hist[w & 3][v.w & 1023], 1u);
    }
    __syncthreads();

    float ps = 0.f, ns = 0.f;
    unsigned long long sqc = 0u;
    const float4* posP4 = (const float4*)posP;
    for (int i = t; i < NPOSB / 4; i += 1024) {
        float4 v = posP4[i];
        ps += (v.x + v.y) + (v.z + v.w);
    }
    if (t < NBLK) ns = negP[t];
    for (int i = t; i < 1024; i += 1024) {
        unsigned long long h = (unsigned long long)hist[0][i] + hist[1][i]
                             + hist[2][i] + hist[3][i];
        sqc += h * h;
    }

    ps = wave_sum_f(ps);
    ns = wave_sum_f(ns);
    #pragma unroll
    for (int o = 32; o >= 1; o >>= 1) sqc += __shfl_xor(sqc, o);

    __shared__ float sp[16], sn[16];
    __shared__ unsigned long long sc[16];
    if (lane == 0) { sp[w] = ps; sn[w] = ns; sc[w] = sqc; }
    __syncthreads();
    if (t == 0) {
        float pos = 0.f, neg = 0.f;
        unsigned long long s2 = 0;
        #pragma unroll
        for (int i = 0; i < 16; ++i) { pos += sp[i]; neg += sn[i]; s2 += sc[i]; }
        unsigned long long nneg = (unsigned long long)NN * NN - s2;
        float ncomp = (float)((unsigned long long)NN + nneg);
        out[0] = (pos + neg) / ncomp;
    }
}

// ---------------------------------------------------------------------------
// ws layout (bytes):
//   up   @ 0        : 131072  (float2[16384]: {u, label})
//   vcp  @ 131072   : 131072  (float2[16384]: {vc, label})
//   ebf  @ 262144   : 2097152
//   posP @ 2359296  : 16384   (NPOSB floats)
//   negP @ 2375680  : 2048    (NBLK=512 floats)
//   total 2377728
// ---------------------------------------------------------------------------
extern "C" void kernel_launch(void* const* d_in, const int* in_sizes, int n_in,
                              void* d_out, int out_size, void* d_ws, size_t ws_size,
                              hipStream_t stream) {
    const float* emb = (const float*)d_in[0];
    const int* lab   = (const int*)d_in[1];
    const int* pidx  = (const int*)d_in[2];
    float* out = (float*)d_out;
    char* ws = (char*)d_ws;
    float2*         up   = (float2*)(ws);
    float2*         vcp  = (float2*)(ws + 131072);
    __hip_bfloat16* ebf  = (__hip_bfloat16*)(ws + 262144);
    float*          posP = (float*)(ws + 2359296);
    float*          negP = (float*)(ws + 2375680);

    norm_kernel<<<NPOSB, 256, 0, stream>>>(emb, pidx, lab, up, vcp, ebf, posP);
    pair_kernel<<<NBLK, 512, 0, stream>>>((const short*)ebf, up, vcp, negP);
    reduce_kernel<<<1, 1024, 0, stream>>>(posP, negP, lab, out);
}